// Round 8
// baseline (473.946 us; speedup 1.0000x reference)
//
#include <hip/hip_runtime.h>
#include <math.h>

#define B_ 32
#define C_ 40000
#define D_ 2048
#define T_SCALE 10.0f
#define P_MARG 0.2f
#define N_MARG 0.3f
#define NBLK (C_ / 16)   // 2500 blocks, 16 cols each
#define NSTEP (D_ / 32)  // 64 k-steps total; 16 per wave

typedef __attribute__((ext_vector_type(4))) float f32x4;
typedef __fp16 fp16x2 __attribute__((ext_vector_type(2)));
typedef _Float16 half8_t __attribute__((ext_vector_type(8)));

// ---- workspace layout (in floats) ----
#define PM_OFF 0                      // pmax [32][NBLK]
#define PM_FLOATS (B_ * NBLK)
#define PS_OFF (PM_OFF + PM_FLOATS)   // psum [32][NBLK]
#define PS_FLOATS (B_ * NBLK)
#define SC_OFF (PS_OFF + PS_FLOATS)   // scalars
#define S_HLOSS 0
#define S_THSUM 1
#define S_THCNT 2
#define S_BAD 3
#define S_NTH 4  // 32 floats
#define S_BU 36  // 32 floats
#define SC_FLOATS 128
#define DT_OFF (SC_OFF + SC_FLOATS)   // raw batch dots [32][32]
#define DT_FLOATS (32 * 32)
#define AF_OFF (DT_OFF + DT_FLOATS)   // A fragments: 64 steps * 8 frags * 64 lanes * 8 f16
#define AF_FLOATS (NSTEP * 4096 / 2)  // 131072 floats = 512KB
#define WS_FLOATS_TOTAL (AF_OFF + AF_FLOATS)

__device__ __forceinline__ float softplus_f(float x) {
    return (x > 0.f) ? (x + log1pf(expf(-x))) : log1pf(expf(x));
}

// split (x0,x1) into packed f16 hi (RTZ) + f16 lo (RTZ of remainder)
__device__ __forceinline__ void split_f16x2(float x0, float x1, unsigned& uh, unsigned& ul) {
    fp16x2 h = __builtin_amdgcn_cvt_pkrtz(x0, x1);
    float r0 = x0 - (float)h[0];
    float r1 = x1 - (float)h[1];
    fp16x2 lo = __builtin_amdgcn_cvt_pkrtz(r0, r1);
    uh = __builtin_bit_cast(unsigned, h);
    ul = __builtin_bit_cast(unsigned, lo);
}

// ---- K0: pack A (rows 0-31 = inputs, 32-63 = V[tgt]) into fragment-major f16 hi/lo ----
// layout (ushort idx): s*4096 + f*512 + lane*8 + j ; f = rb (hi) or 4+rb (lo)
__global__ __launch_bounds__(256) void build_Afrag(const float* __restrict__ in,
                                                   const float* __restrict__ V,
                                                   const int* __restrict__ tgt,
                                                   unsigned short* __restrict__ Af) {
    int s = blockIdx.x;           // 0..63
    int rb = threadIdx.x >> 6;    // 0..3
    int l = threadIdx.x & 63;
    int row = rb * 16 + (l & 15);
    int k = s * 32 + (l >> 4) * 8;
    const float* src = (row < 32) ? (in + (size_t)row * D_ + k)
                                  : (V + (size_t)tgt[row - 32] * D_ + k);
    f32x4 x0 = *(const f32x4*)src;
    f32x4 x1 = *(const f32x4*)(src + 4);
    unsigned uh0, ul0, uh1, ul1, uh2, ul2, uh3, ul3;
    split_f16x2(x0[0], x0[1], uh0, ul0);
    split_f16x2(x0[2], x0[3], uh1, ul1);
    split_f16x2(x1[0], x1[1], uh2, ul2);
    split_f16x2(x1[2], x1[3], uh3, ul3);
    size_t base = (size_t)s * 4096 + (size_t)l * 8;
    *(uint4*)(Af + base + rb * 512) = make_uint4(uh0, uh1, uh2, uh3);
    *(uint4*)(Af + base + (4 + rb) * 512) = make_uint4(ul0, ul1, ul2, ul3);
}

// ---- K1b: raw 32x32 batch dots ----
__global__ __launch_bounds__(256) void sims_dots(const float* __restrict__ in,
                                                 float* __restrict__ dt) {
    __shared__ float part[8][32];
    int i = blockIdx.x;
    int j = threadIdx.x & 31;
    int sl = threadIdx.x >> 5;
    const float4* a4 = (const float4*)(in + (size_t)i * D_ + sl * 256);
    const float4* b4 = (const float4*)(in + (size_t)j * D_ + sl * 256);
    float s = 0.f;
#pragma unroll 4
    for (int k = 0; k < 64; ++k) {
        float4 x = a4[k], y = b4[k];
        s += x.x * y.x + x.y * y.y + x.z * y.z + x.w * y.w;
    }
    part[sl][j] = s;
    __syncthreads();
    if (threadIdx.x < 32) {
        float t = 0.f;
#pragma unroll
        for (int p = 0; p < 8; ++p) t += part[p][threadIdx.x];
        dt[i * 32 + threadIdx.x] = t;
    }
}

// ---- K1c: sims, thresholds, h_loss, n_th_t ----
__global__ __launch_bounds__(1024) void small_finish(const float* __restrict__ in,
                                                     const float* __restrict__ V,
                                                     const int* __restrict__ tgt,
                                                     float* __restrict__ ws) {
    __shared__ float sims[32][33];
    __shared__ float nthr[32], pthr[32];
    __shared__ int ts[32];
    __shared__ float diag[32];
    __shared__ float red[4];
    int tid = threadIdx.x;
    int i = tid >> 5, j = tid & 31;
    const float* dt = ws + DT_OFF;
    if (tid < 32) { ts[tid] = tgt[tid]; diag[tid] = dt[tid * 32 + tid]; }
    if (tid < 4) red[tid] = 0.f;
    __syncthreads();
    float sim = dt[i * 32 + j] * rsqrtf(diag[i] * diag[j]);
    sims[i][j] = sim;
    __syncthreads();
    if (tid < 32) {
        float nmin = 2.f, pmax = -2.f;
        int ti = ts[tid];
        for (int jj = 0; jj < 32; ++jj) {
            bool pos = (ts[jj] == ti) && (jj != tid);
            float v = sims[tid][jj];
            if (pos) { nmin = fminf(nmin, v); pmax = fmaxf(pmax, v); }
        }
        nthr[tid] = nmin - N_MARG;
        pthr[tid] = pmax - P_MARG;
    }
    __syncthreads();
    bool pos = (ts[i] == ts[j]) && (i != j);
    bool neg = (ts[i] != ts[j]);
    if (pos && sim < pthr[i]) { atomicAdd(&red[0], softplus_f(-sim)); atomicAdd(&red[1], 1.f); }
    if (neg && sim > nthr[i]) { atomicAdd(&red[2], softplus_f(sim)); atomicAdd(&red[3], 1.f); }

    const float4* a4 = (const float4*)(in + (size_t)i * D_);
    const float4* v4 = (const float4*)(V + (size_t)ts[i] * D_);
    float sn = 0.f;
    for (int k = j; k < D_ / 4; k += 32) {
        float4 x = a4[k], y = v4[k];
        sn += x.x * y.x + x.y * y.y + x.z * y.z + x.w * y.w;
    }
    for (int off = 16; off > 0; off >>= 1) sn += __shfl_down(sn, off, 32);
    if (j == 0) ws[SC_OFF + S_NTH + i] = sn * rsqrtf(diag[i]) - N_MARG;
    __syncthreads();
    if (tid == 0) {
        float h = 0.f;
        if (red[1] > 0.f) h += red[0] / red[1];
        if (red[3] > 0.f) h += red[2] / red[3];
        ws[SC_OFF + S_HLOSS] = h;
    }
}

// ---- epilogue helpers ----
__device__ __forceinline__ void out_tile(f32x4 a, int rowbase, int g, int col, int n0,
                                         int wid, float* __restrict__ out,
                                         float* __restrict__ ws) {
#pragma unroll
    for (int r = 0; r < 4; ++r) {
        int row = rowbase + g * 4 + r;
        float y = a[r] * T_SCALE;
        out[(size_t)row * C_ + n0 + col] = y;
        float gm = y;
        gm = fmaxf(gm, __shfl_xor(gm, 1));
        gm = fmaxf(gm, __shfl_xor(gm, 2));
        gm = fmaxf(gm, __shfl_xor(gm, 4));
        gm = fmaxf(gm, __shfl_xor(gm, 8));
        float es = expf(y - gm);
        es += __shfl_xor(es, 1);
        es += __shfl_xor(es, 2);
        es += __shfl_xor(es, 4);
        es += __shfl_xor(es, 8);
        if (col == 0) {
            ws[PM_OFF + (size_t)row * NBLK + wid] = gm;
            ws[PS_OFF + (size_t)row * NBLK + wid] = es;
        }
    }
}

__device__ __forceinline__ void th_tile(f32x4 a, int bbase, int g, const float* __restrict__ nthp,
                                        float& ts, float& tc) {
#pragma unroll
    for (int r = 0; r < 4; ++r) {
        int b = bbase + g * 4 + r;
        float x = a[r];
        float nth = nthp[b];
        if (x > nth && x < 0.9999f) { ts += softplus_f(x); tc += 1.f; }
    }
}

// ---- K2: MFMA GEMM. Block = 16 cols; 4 waves split K (16 steps each);
//      LDS cross-wave reduce; wave w does acc-group w's epilogue. TLP-driven.
__global__ __launch_bounds__(256) void gemm_mfma(const float* __restrict__ V,
                                                 const unsigned short* __restrict__ Af,
                                                 float* __restrict__ out,
                                                 float* __restrict__ ws) {
    __shared__ float4 redl[4][4][64]; // [acc group][wave][lane]
    __shared__ float vs_lds[4][16];
    const int l = threadIdx.x & 63;
    const int w = threadIdx.x >> 6;
    const int wid = blockIdx.x;
    const int col = l & 15, g = l >> 4;
    const int n0 = wid * 16;
    const float* vp = V + (size_t)(n0 + col) * D_ + g * 8;
    const unsigned short* afp = Af + (size_t)l * 8;

    f32x4 acc0 = {0.f, 0.f, 0.f, 0.f};
    f32x4 acc1 = acc0, acc2 = acc0, acc3 = acc0;
    float vsum = 0.f;

    const int s0 = w * (NSTEP / 4);
    for (int s = s0; s < s0 + NSTEP / 4; ++s) {
        f32x4 v0 = *(const f32x4*)(vp + s * 32);
        f32x4 v1 = *(const f32x4*)(vp + s * 32 + 4);
        const unsigned short* ap = afp + (size_t)s * 4096;
        uint4 a0 = *(const uint4*)(ap + 0 * 512);
        uint4 a1 = *(const uint4*)(ap + 1 * 512);
        uint4 a2 = *(const uint4*)(ap + 2 * 512);
        uint4 a3 = *(const uint4*)(ap + 3 * 512);
        uint4 a4 = *(const uint4*)(ap + 4 * 512);
        uint4 a5 = *(const uint4*)(ap + 5 * 512);
        uint4 a6 = *(const uint4*)(ap + 6 * 512);
        uint4 a7 = *(const uint4*)(ap + 7 * 512);

        vsum += v0[0] + v0[1] + v0[2] + v0[3] + v1[0] + v1[1] + v1[2] + v1[3];
        unsigned uh0, ul0, uh1, ul1, uh2, ul2, uh3, ul3;
        split_f16x2(v0[0], v0[1], uh0, ul0);
        split_f16x2(v0[2], v0[3], uh1, ul1);
        split_f16x2(v1[0], v1[1], uh2, ul2);
        split_f16x2(v1[2], v1[3], uh3, ul3);
        half8_t bh = __builtin_bit_cast(half8_t, make_uint4(uh0, uh1, uh2, uh3));
        half8_t bl = __builtin_bit_cast(half8_t, make_uint4(ul0, ul1, ul2, ul3));

        half8_t a0h = __builtin_bit_cast(half8_t, a0);
        half8_t a1h = __builtin_bit_cast(half8_t, a1);
        half8_t a2h = __builtin_bit_cast(half8_t, a2);
        half8_t a3h = __builtin_bit_cast(half8_t, a3);
        half8_t a0l = __builtin_bit_cast(half8_t, a4);
        half8_t a1l = __builtin_bit_cast(half8_t, a5);
        half8_t a2l = __builtin_bit_cast(half8_t, a6);
        half8_t a3l = __builtin_bit_cast(half8_t, a7);

        acc0 = __builtin_amdgcn_mfma_f32_16x16x32_f16(a0h, bh, acc0, 0, 0, 0);
        acc1 = __builtin_amdgcn_mfma_f32_16x16x32_f16(a1h, bh, acc1, 0, 0, 0);
        acc2 = __builtin_amdgcn_mfma_f32_16x16x32_f16(a2h, bh, acc2, 0, 0, 0);
        acc3 = __builtin_amdgcn_mfma_f32_16x16x32_f16(a3h, bh, acc3, 0, 0, 0);
        acc0 = __builtin_amdgcn_mfma_f32_16x16x32_f16(a0h, bl, acc0, 0, 0, 0);
        acc1 = __builtin_amdgcn_mfma_f32_16x16x32_f16(a1h, bl, acc1, 0, 0, 0);
        acc2 = __builtin_amdgcn_mfma_f32_16x16x32_f16(a2h, bl, acc2, 0, 0, 0);
        acc3 = __builtin_amdgcn_mfma_f32_16x16x32_f16(a3h, bl, acc3, 0, 0, 0);
        acc0 = __builtin_amdgcn_mfma_f32_16x16x32_f16(a0l, bh, acc0, 0, 0, 0);
        acc1 = __builtin_amdgcn_mfma_f32_16x16x32_f16(a1l, bh, acc1, 0, 0, 0);
        acc2 = __builtin_amdgcn_mfma_f32_16x16x32_f16(a2l, bh, acc2, 0, 0, 0);
        acc3 = __builtin_amdgcn_mfma_f32_16x16x32_f16(a3l, bh, acc3, 0, 0, 0);
    }

    // stash partial accs for cross-wave reduce
    redl[0][w][l] = make_float4(acc0[0], acc0[1], acc0[2], acc0[3]);
    redl[1][w][l] = make_float4(acc1[0], acc1[1], acc1[2], acc1[3]);
    redl[2][w][l] = make_float4(acc2[0], acc2[1], acc2[2], acc2[3]);
    redl[3][w][l] = make_float4(acc3[0], acc3[1], acc3[2], acc3[3]);

    // per-wave vsum over this K-chunk -> per-col partial
    vsum += __shfl_xor(vsum, 16);
    vsum += __shfl_xor(vsum, 32);
    if (l < 16) vs_lds[w][l] = vsum;
    __syncthreads();

    // V row-sum zero check (full K), done once
    if (threadIdx.x < 16) {
        float t = vs_lds[0][threadIdx.x] + vs_lds[1][threadIdx.x] +
                  vs_lds[2][threadIdx.x] + vs_lds[3][threadIdx.x];
        if (t == 0.0f) ws[SC_OFF + S_BAD] = 1.0f;
    }

    // wave w: sum acc-group w across the 4 K-chunks
    float4 p0 = redl[w][0][l], p1 = redl[w][1][l], p2 = redl[w][2][l], p3 = redl[w][3][l];
    f32x4 acc = {p0.x + p1.x + p2.x + p3.x, p0.y + p1.y + p2.y + p3.y,
                 p0.z + p1.z + p2.z + p3.z, p0.w + p1.w + p2.w + p3.w};

    if (w == 0) {
        out_tile(acc, 0, g, col, n0, wid, out, ws);
    } else if (w == 1) {
        out_tile(acc, 16, g, col, n0, wid, out, ws);
    } else {
        float ts = 0.f, tc = 0.f;
        const float* nthp = ws + SC_OFF + S_NTH;
        th_tile(acc, (w - 2) * 16, g, nthp, ts, tc);
#pragma unroll
        for (int off = 32; off >= 1; off >>= 1) {
            ts += __shfl_xor(ts, off);
            tc += __shfl_xor(tc, off);
        }
        if (l == 0 && tc != 0.f) {
            atomicAdd(&ws[SC_OFF + S_THSUM], ts);
            atomicAdd(&ws[SC_OFF + S_THCNT], tc);
        }
    }
}

// ---- K3: combine lse partials, bu term ----
__global__ __launch_bounds__(256) void lse_combine(const float* __restrict__ out,
                                                   const int* __restrict__ tgt,
                                                   float* __restrict__ ws) {
    int b = blockIdx.x;
    int tid = threadIdx.x;
    __shared__ float sm[256];
    const float* pm = ws + PM_OFF + (size_t)b * NBLK;
    const float* ps = ws + PS_OFF + (size_t)b * NBLK;
    float m = -INFINITY;
    for (int i = tid; i < NBLK; i += 256) m = fmaxf(m, pm[i]);
    sm[tid] = m;
    __syncthreads();
    for (int s = 128; s > 0; s >>= 1) {
        if (tid < s) sm[tid] = fmaxf(sm[tid], sm[tid + s]);
        __syncthreads();
    }
    float M = sm[0];
    __syncthreads();
    float s = 0.f;
    for (int i = tid; i < NBLK; i += 256) s += ps[i] * expf(pm[i] - M);
    sm[tid] = s;
    __syncthreads();
    for (int st = 128; st > 0; st >>= 1) {
        if (tid < st) sm[tid] += sm[tid + st];
        __syncthreads();
    }
    if (tid == 0) {
        float lse = M + logf(sm[0]);
        ws[SC_OFF + S_BU + b] = lse - out[(size_t)b * C_ + tgt[b]];
    }
}

// ---- K5: combine ----
__global__ void finalize(const float* __restrict__ ws, float* __restrict__ out0) {
    if (threadIdx.x == 0 && blockIdx.x == 0) {
        float bu = 0.f;
        for (int b = 0; b < 32; ++b) bu += ws[SC_OFF + S_BU + b];
        bu /= 32.f;
        float h = ws[SC_OFF + S_HLOSS];
        float th = 0.f;
        float cnt = ws[SC_OFF + S_THCNT];
        if (ws[SC_OFF + S_BAD] == 0.f && cnt > 0.f) th = ws[SC_OFF + S_THSUM] / cnt;
        out0[0] = 1.0f * bu + 1.0f * h + 3.0f * th;
    }
}

extern "C" void kernel_launch(void* const* d_in, const int* in_sizes, int n_in,
                              void* d_out, int out_size, void* d_ws, size_t ws_size,
                              hipStream_t stream) {
    const float* in = (const float*)d_in[0];
    const float* V = (const float*)d_in[1];
    const int* tgt = (const int*)d_in[2];
    float* outp = (float*)d_out;
    float* ws = (float*)d_ws;
    unsigned short* Af = (unsigned short*)(ws + AF_OFF);

    (void)hipMemsetAsync((void*)(ws + SC_OFF), 0, SC_FLOATS * sizeof(float), stream);

    build_Afrag<<<NSTEP, 256, 0, stream>>>(in, V, tgt, Af);
    sims_dots<<<32, 256, 0, stream>>>(in, ws + DT_OFF);
    small_finish<<<1, 1024, 0, stream>>>(in, V, tgt, ws);

    gemm_mfma<<<NBLK, 256, 0, stream>>>(V, Af, outp + 1, ws);

    lse_combine<<<B_, 256, 0, stream>>>(outp + 1, tgt, ws);
    finalize<<<1, 64, 0, stream>>>(ws, outp);
}

// Round 9
// 222.648 us; speedup vs baseline: 2.1287x; 2.1287x over previous
//
#include <hip/hip_runtime.h>
#include <math.h>

#define B_ 32
#define C_ 40000
#define D_ 2048
#define T_SCALE 10.0f
#define P_MARG 0.2f
#define N_MARG 0.3f
#define NBLK (C_ / 16)   // 2500 col-groups (16 cols each)
#define NSTEP (D_ / 32)  // 64 k-steps of K=32

typedef __attribute__((ext_vector_type(4))) float f32x4;
typedef __fp16 fp16x2 __attribute__((ext_vector_type(2)));
typedef _Float16 half8_t __attribute__((ext_vector_type(8)));

// async global->LDS, 16B per lane; LDS dest = wave-uniform base + lane*16
#define GLL(gsrc, ldst)                                                          \
    __builtin_amdgcn_global_load_lds(                                            \
        (const __attribute__((address_space(1))) unsigned int*)(gsrc),           \
        (__attribute__((address_space(3))) unsigned int*)(ldst), 16, 0, 0)

// ---- workspace layout (in floats) ----
#define PM_OFF 0                      // pmax [32][NBLK]
#define PM_FLOATS (B_ * NBLK)
#define PS_OFF (PM_OFF + PM_FLOATS)   // psum [32][NBLK]
#define PS_FLOATS (B_ * NBLK)
#define SC_OFF (PS_OFF + PS_FLOATS)   // scalars
#define S_HLOSS 0
#define S_THSUM 1
#define S_THCNT 2
#define S_BAD 3
#define S_NTH 4  // 32 floats
#define S_BU 36  // 32 floats
#define SC_FLOATS 128
#define DT_OFF (SC_OFF + SC_FLOATS)   // raw batch dots [32][32]
#define DT_FLOATS (32 * 32)
#define AF_OFF (DT_OFF + DT_FLOATS)   // A fragments: 64 steps * 8 frags * 64 lanes * 8 f16
#define AF_FLOATS (NSTEP * 4096 / 2)  // 131072 floats = 512KB
#define WS_FLOATS_TOTAL (AF_OFF + AF_FLOATS)

__device__ __forceinline__ float softplus_f(float x) {
    return (x > 0.f) ? (x + log1pf(expf(-x))) : log1pf(expf(x));
}

// split (x0,x1) into packed f16 hi (RTZ) + f16 lo (RTZ of remainder)
__device__ __forceinline__ void split_f16x2(float x0, float x1, unsigned& uh, unsigned& ul) {
    fp16x2 h = __builtin_amdgcn_cvt_pkrtz(x0, x1);
    float r0 = x0 - (float)h[0];
    float r1 = x1 - (float)h[1];
    fp16x2 lo = __builtin_amdgcn_cvt_pkrtz(r0, r1);
    uh = __builtin_bit_cast(unsigned, h);
    ul = __builtin_bit_cast(unsigned, lo);
}

// ---- K0: pack A (rows 0-31 = inputs, 32-63 = V[tgt]) into fragment-major f16 hi/lo ----
// layout (ushort idx): s*4096 + f*512 + lane*8 + j ; f = rb (hi) or 4+rb (lo)
__global__ __launch_bounds__(256) void build_Afrag(const float* __restrict__ in,
                                                   const float* __restrict__ V,
                                                   const int* __restrict__ tgt,
                                                   unsigned short* __restrict__ Af) {
    int s = blockIdx.x;           // 0..63
    int rb = threadIdx.x >> 6;    // 0..3
    int l = threadIdx.x & 63;
    int row = rb * 16 + (l & 15);
    int k = s * 32 + (l >> 4) * 8;
    const float* src = (row < 32) ? (in + (size_t)row * D_ + k)
                                  : (V + (size_t)tgt[row - 32] * D_ + k);
    f32x4 x0 = *(const f32x4*)src;
    f32x4 x1 = *(const f32x4*)(src + 4);
    unsigned uh0, ul0, uh1, ul1, uh2, ul2, uh3, ul3;
    split_f16x2(x0[0], x0[1], uh0, ul0);
    split_f16x2(x0[2], x0[3], uh1, ul1);
    split_f16x2(x1[0], x1[1], uh2, ul2);
    split_f16x2(x1[2], x1[3], uh3, ul3);
    size_t base = (size_t)s * 4096 + (size_t)l * 8;
    *(uint4*)(Af + base + rb * 512) = make_uint4(uh0, uh1, uh2, uh3);
    *(uint4*)(Af + base + (4 + rb) * 512) = make_uint4(ul0, ul1, ul2, ul3);
}

// ---- K1b: raw 32x32 batch dots ----
__global__ __launch_bounds__(256) void sims_dots(const float* __restrict__ in,
                                                 float* __restrict__ dt) {
    __shared__ float part[8][32];
    int i = blockIdx.x;
    int j = threadIdx.x & 31;
    int sl = threadIdx.x >> 5;
    const float4* a4 = (const float4*)(in + (size_t)i * D_ + sl * 256);
    const float4* b4 = (const float4*)(in + (size_t)j * D_ + sl * 256);
    float s = 0.f;
#pragma unroll 4
    for (int k = 0; k < 64; ++k) {
        float4 x = a4[k], y = b4[k];
        s += x.x * y.x + x.y * y.y + x.z * y.z + x.w * y.w;
    }
    part[sl][j] = s;
    __syncthreads();
    if (threadIdx.x < 32) {
        float t = 0.f;
#pragma unroll
        for (int p = 0; p < 8; ++p) t += part[p][threadIdx.x];
        dt[i * 32 + threadIdx.x] = t;
    }
}

// ---- K1c: sims, thresholds, h_loss, n_th_t ----
__global__ __launch_bounds__(1024) void small_finish(const float* __restrict__ in,
                                                     const float* __restrict__ V,
                                                     const int* __restrict__ tgt,
                                                     float* __restrict__ ws) {
    __shared__ float sims[32][33];
    __shared__ float nthr[32], pthr[32];
    __shared__ int ts[32];
    __shared__ float diag[32];
    __shared__ float red[4];
    int tid = threadIdx.x;
    int i = tid >> 5, j = tid & 31;
    const float* dt = ws + DT_OFF;
    if (tid < 32) { ts[tid] = tgt[tid]; diag[tid] = dt[tid * 32 + tid]; }
    if (tid < 4) red[tid] = 0.f;
    __syncthreads();
    float sim = dt[i * 32 + j] * rsqrtf(diag[i] * diag[j]);
    sims[i][j] = sim;
    __syncthreads();
    if (tid < 32) {
        float nmin = 2.f, pmax = -2.f;
        int ti = ts[tid];
        for (int jj = 0; jj < 32; ++jj) {
            bool pos = (ts[jj] == ti) && (jj != tid);
            float v = sims[tid][jj];
            if (pos) { nmin = fminf(nmin, v); pmax = fmaxf(pmax, v); }
        }
        nthr[tid] = nmin - N_MARG;
        pthr[tid] = pmax - P_MARG;
    }
    __syncthreads();
    bool pos = (ts[i] == ts[j]) && (i != j);
    bool neg = (ts[i] != ts[j]);
    if (pos && sim < pthr[i]) { atomicAdd(&red[0], softplus_f(-sim)); atomicAdd(&red[1], 1.f); }
    if (neg && sim > nthr[i]) { atomicAdd(&red[2], softplus_f(sim)); atomicAdd(&red[3], 1.f); }

    const float4* a4 = (const float4*)(in + (size_t)i * D_);
    const float4* v4 = (const float4*)(V + (size_t)ts[i] * D_);
    float sn = 0.f;
    for (int k = j; k < D_ / 4; k += 32) {
        float4 x = a4[k], y = v4[k];
        sn += x.x * y.x + x.y * y.y + x.z * y.z + x.w * y.w;
    }
    for (int off = 16; off > 0; off >>= 1) sn += __shfl_down(sn, off, 32);
    if (j == 0) ws[SC_OFF + S_NTH + i] = sn * rsqrtf(diag[i]) - N_MARG;
    __syncthreads();
    if (tid == 0) {
        float h = 0.f;
        if (red[1] > 0.f) h += red[0] / red[1];
        if (red[3] > 0.f) h += red[2] / red[3];
        ws[SC_OFF + S_HLOSS] = h;
    }
}

// ---- epilogue helpers ----
__device__ __forceinline__ void out_tile(f32x4 a, int rowbase, int g, int col, int n0,
                                         int wid, float* __restrict__ out,
                                         float* __restrict__ ws) {
#pragma unroll
    for (int r = 0; r < 4; ++r) {
        int row = rowbase + g * 4 + r;
        float y = a[r] * T_SCALE;
        out[(size_t)row * C_ + n0 + col] = y;
        float gm = y;
        gm = fmaxf(gm, __shfl_xor(gm, 1));
        gm = fmaxf(gm, __shfl_xor(gm, 2));
        gm = fmaxf(gm, __shfl_xor(gm, 4));
        gm = fmaxf(gm, __shfl_xor(gm, 8));
        float es = expf(y - gm);
        es += __shfl_xor(es, 1);
        es += __shfl_xor(es, 2);
        es += __shfl_xor(es, 4);
        es += __shfl_xor(es, 8);
        if (col == 0) {
            ws[PM_OFF + (size_t)row * NBLK + wid] = gm;
            ws[PS_OFF + (size_t)row * NBLK + wid] = es;
        }
    }
}

__device__ __forceinline__ void th_tile(f32x4 a, int bbase, int g, const float* __restrict__ nthp,
                                        float& ts, float& tc) {
#pragma unroll
    for (int r = 0; r < 4; ++r) {
        int b = bbase + g * 4 + r;
        float x = a[r];
        float nth = nthp[b];
        if (x > nth && x < 0.9999f) { ts += softplus_f(x); tc += 1.f; }
    }
}

// ---- K2: MFMA GEMM, 2-phase global_load_lds pipeline.
//      Block = 64 cols (4 waves x 16 cols, each wave owns its cols fully).
//      Per step: stage next A-frag + V tiles into LDS (async, zero VGPR),
//      ds_read current tile, split V to f16 hi/lo, 12 MFMA. One barrier/step.
__global__ __launch_bounds__(256) void gemm_mfma(const float* __restrict__ V,
                                                 const unsigned short* __restrict__ Af,
                                                 float* __restrict__ out,
                                                 float* __restrict__ ws) {
    __shared__ unsigned short Albs[2][8][512]; // [buf][frag][1KB]  = 8KB/buf
    __shared__ float Vlbs[2][64][32];          // [buf][row][128B]  = 8KB/buf
    const int l = threadIdx.x & 63;
    const int w = threadIdx.x >> 6;
    const int wid = blockIdx.x * 4 + w;
    const int col = l & 15, g = l >> 4;
    const int n0blk = blockIdx.x * 64;
    const int n0 = wid * 16;

    f32x4 acc0 = {0.f, 0.f, 0.f, 0.f};
    f32x4 acc1 = acc0, acc2 = acc0, acc3 = acc0;
    float vsum = 0.f;

    const int f0 = 2 * w;
    const int vrow0 = 16 * w + (l >> 3);
    const int vcol0 = (l & 7) * 4;

    // prologue: stage step 0 into buf 0
    {
        GLL(Af + (size_t)0 * 4096 + (size_t)f0 * 512 + l * 8, &Albs[0][f0][0]);
        GLL(Af + (size_t)0 * 4096 + (size_t)(f0 + 1) * 512 + l * 8, &Albs[0][f0 + 1][0]);
        GLL(V + (size_t)(n0blk + vrow0) * D_ + vcol0, &Vlbs[0][16 * w][0]);
        GLL(V + (size_t)(n0blk + vrow0 + 8) * D_ + vcol0, &Vlbs[0][16 * w + 8][0]);
    }
    __syncthreads();

    int cur = 0;
    for (int t = 0; t < NSTEP; ++t) {
        // stage next tile into buf^1 (overlaps with this step's compute)
        if (t + 1 < NSTEP) {
            const int nb = cur ^ 1;
            const size_t sa = (size_t)(t + 1) * 4096;
            const size_t sv = (size_t)(t + 1) * 32;
            GLL(Af + sa + (size_t)f0 * 512 + l * 8, &Albs[nb][f0][0]);
            GLL(Af + sa + (size_t)(f0 + 1) * 512 + l * 8, &Albs[nb][f0 + 1][0]);
            GLL(V + (size_t)(n0blk + vrow0) * D_ + sv + vcol0, &Vlbs[nb][16 * w][0]);
            GLL(V + (size_t)(n0blk + vrow0 + 8) * D_ + sv + vcol0, &Vlbs[nb][16 * w + 8][0]);
        }

        // current tile from LDS
        uint4 a0 = *(const uint4*)&Albs[cur][0][l * 8];
        uint4 a1 = *(const uint4*)&Albs[cur][1][l * 8];
        uint4 a2 = *(const uint4*)&Albs[cur][2][l * 8];
        uint4 a3 = *(const uint4*)&Albs[cur][3][l * 8];
        uint4 a4 = *(const uint4*)&Albs[cur][4][l * 8];
        uint4 a5 = *(const uint4*)&Albs[cur][5][l * 8];
        uint4 a6 = *(const uint4*)&Albs[cur][6][l * 8];
        uint4 a7 = *(const uint4*)&Albs[cur][7][l * 8];
        f32x4 v0 = *(const f32x4*)&Vlbs[cur][16 * w + col][g * 8];
        f32x4 v1 = *(const f32x4*)&Vlbs[cur][16 * w + col][g * 8 + 4];

        vsum += v0[0] + v0[1] + v0[2] + v0[3] + v1[0] + v1[1] + v1[2] + v1[3];
        unsigned uh0, ul0, uh1, ul1, uh2, ul2, uh3, ul3;
        split_f16x2(v0[0], v0[1], uh0, ul0);
        split_f16x2(v0[2], v0[3], uh1, ul1);
        split_f16x2(v1[0], v1[1], uh2, ul2);
        split_f16x2(v1[2], v1[3], uh3, ul3);
        half8_t bh = __builtin_bit_cast(half8_t, make_uint4(uh0, uh1, uh2, uh3));
        half8_t bl = __builtin_bit_cast(half8_t, make_uint4(ul0, ul1, ul2, ul3));

        half8_t a0h = __builtin_bit_cast(half8_t, a0);
        half8_t a1h = __builtin_bit_cast(half8_t, a1);
        half8_t a2h = __builtin_bit_cast(half8_t, a2);
        half8_t a3h = __builtin_bit_cast(half8_t, a3);
        half8_t a0l = __builtin_bit_cast(half8_t, a4);
        half8_t a1l = __builtin_bit_cast(half8_t, a5);
        half8_t a2l = __builtin_bit_cast(half8_t, a6);
        half8_t a3l = __builtin_bit_cast(half8_t, a7);

        acc0 = __builtin_amdgcn_mfma_f32_16x16x32_f16(a0h, bh, acc0, 0, 0, 0);
        acc1 = __builtin_amdgcn_mfma_f32_16x16x32_f16(a1h, bh, acc1, 0, 0, 0);
        acc2 = __builtin_amdgcn_mfma_f32_16x16x32_f16(a2h, bh, acc2, 0, 0, 0);
        acc3 = __builtin_amdgcn_mfma_f32_16x16x32_f16(a3h, bh, acc3, 0, 0, 0);
        acc0 = __builtin_amdgcn_mfma_f32_16x16x32_f16(a0h, bl, acc0, 0, 0, 0);
        acc1 = __builtin_amdgcn_mfma_f32_16x16x32_f16(a1h, bl, acc1, 0, 0, 0);
        acc2 = __builtin_amdgcn_mfma_f32_16x16x32_f16(a2h, bl, acc2, 0, 0, 0);
        acc3 = __builtin_amdgcn_mfma_f32_16x16x32_f16(a3h, bl, acc3, 0, 0, 0);
        acc0 = __builtin_amdgcn_mfma_f32_16x16x32_f16(a0l, bh, acc0, 0, 0, 0);
        acc1 = __builtin_amdgcn_mfma_f32_16x16x32_f16(a1l, bh, acc1, 0, 0, 0);
        acc2 = __builtin_amdgcn_mfma_f32_16x16x32_f16(a2l, bh, acc2, 0, 0, 0);
        acc3 = __builtin_amdgcn_mfma_f32_16x16x32_f16(a3l, bh, acc3, 0, 0, 0);

        __syncthreads(); // drains vmcnt(0): next tile landed; all reads of cur done
        cur ^= 1;
    }

    // V row-sum zero check (full K, this wave's 16 cols)
    vsum += __shfl_xor(vsum, 16);
    vsum += __shfl_xor(vsum, 32);
    if (g == 0 && vsum == 0.0f) ws[SC_OFF + S_BAD] = 1.0f;

    // outputs rows 0..31 (+ lse partials)
    out_tile(acc0, 0, g, col, n0, wid, out, ws);
    out_tile(acc1, 16, g, col, n0, wid, out, ws);

    // th term from nsims accumulators (rows 32..63)
    float ts = 0.f, tc = 0.f;
    const float* nthp = ws + SC_OFF + S_NTH;
    th_tile(acc2, 0, g, nthp, ts, tc);
    th_tile(acc3, 16, g, nthp, ts, tc);
#pragma unroll
    for (int off = 32; off >= 1; off >>= 1) {
        ts += __shfl_xor(ts, off);
        tc += __shfl_xor(tc, off);
    }
    if (l == 0 && tc != 0.f) {
        atomicAdd(&ws[SC_OFF + S_THSUM], ts);
        atomicAdd(&ws[SC_OFF + S_THCNT], tc);
    }
}

// ---- K3: combine lse partials, bu term ----
__global__ __launch_bounds__(256) void lse_combine(const float* __restrict__ out,
                                                   const int* __restrict__ tgt,
                                                   float* __restrict__ ws) {
    int b = blockIdx.x;
    int tid = threadIdx.x;
    __shared__ float sm[256];
    const float* pm = ws + PM_OFF + (size_t)b * NBLK;
    const float* ps = ws + PS_OFF + (size_t)b * NBLK;
    float m = -INFINITY;
    for (int i = tid; i < NBLK; i += 256) m = fmaxf(m, pm[i]);
    sm[tid] = m;
    __syncthreads();
    for (int s = 128; s > 0; s >>= 1) {
        if (tid < s) sm[tid] = fmaxf(sm[tid], sm[tid + s]);
        __syncthreads();
    }
    float M = sm[0];
    __syncthreads();
    float s = 0.f;
    for (int i = tid; i < NBLK; i += 256) s += ps[i] * expf(pm[i] - M);
    sm[tid] = s;
    __syncthreads();
    for (int st = 128; st > 0; st >>= 1) {
        if (tid < st) sm[tid] += sm[tid + st];
        __syncthreads();
    }
    if (tid == 0) {
        float lse = M + logf(sm[0]);
        ws[SC_OFF + S_BU + b] = lse - out[(size_t)b * C_ + tgt[b]];
    }
}

// ---- K5: combine ----
__global__ void finalize(const float* __restrict__ ws, float* __restrict__ out0) {
    if (threadIdx.x == 0 && blockIdx.x == 0) {
        float bu = 0.f;
        for (int b = 0; b < 32; ++b) bu += ws[SC_OFF + S_BU + b];
        bu /= 32.f;
        float h = ws[SC_OFF + S_HLOSS];
        float th = 0.f;
        float cnt = ws[SC_OFF + S_THCNT];
        if (ws[SC_OFF + S_BAD] == 0.f && cnt > 0.f) th = ws[SC_OFF + S_THSUM] / cnt;
        out0[0] = 1.0f * bu + 1.0f * h + 3.0f * th;
    }
}

extern "C" void kernel_launch(void* const* d_in, const int* in_sizes, int n_in,
                              void* d_out, int out_size, void* d_ws, size_t ws_size,
                              hipStream_t stream) {
    const float* in = (const float*)d_in[0];
    const float* V = (const float*)d_in[1];
    const int* tgt = (const int*)d_in[2];
    float* outp = (float*)d_out;
    float* ws = (float*)d_ws;
    unsigned short* Af = (unsigned short*)(ws + AF_OFF);

    (void)hipMemsetAsync((void*)(ws + SC_OFF), 0, SC_FLOATS * sizeof(float), stream);

    build_Afrag<<<NSTEP, 256, 0, stream>>>(in, V, tgt, Af);
    sims_dots<<<32, 256, 0, stream>>>(in, ws + DT_OFF);
    small_finish<<<1, 1024, 0, stream>>>(in, V, tgt, ws);

    gemm_mfma<<<NBLK / 4, 256, 0, stream>>>(V, Af, outp + 1, ws);

    lse_combine<<<B_, 256, 0, stream>>>(outp + 1, tgt, ws);
    finalize<<<1, 64, 0, stream>>>(ws, outp);
}